// Round 3
// baseline (238.153 us; speedup 1.0000x reference)
//
#include <hip/hip_runtime.h>
#include <math.h>

#define NROWS 16384
#define DDIM  2048
#define EEXP  64
#define RB    32                 // rows per block -> grid 512 = 2 blocks/CU
#define KC    64                 // k-columns per chunk
#define NCH   (DDIM / KC)        // 32 chunks

// d_ws layout: W pre-split into 3 bf16 levels, fragment-ordered.
// frag addr = ((((c*4 + kg)*2 + et)*64 + lane)*48) + lvl*16
// -> per chunk, wave (kg,et) reads 64 lanes x 48B = 3KB contiguous. 768 KB total.
#define WSPLIT_BYTES 786432
#define CHSTRIDE     24576       // 4 kg * 2 et * 64 lanes * 48 B

typedef short  bf16x8 __attribute__((ext_vector_type(8)));   // 8 bf16 = 4 VGPR
typedef float  f32x16 __attribute__((ext_vector_type(16)));  // 32x32 accum

union V4 { uint4 u; bf16x8 s; };

// Truncating 3-way bf16 split of two floats, packed pairwise per level.
// f = X0 + X1 + X2 + eps, |eps| <= 2^-24 |f| (subs exact: same-exponent tails)
static __device__ __forceinline__ void split3x2(float f0, float f1,
                                                unsigned int &p0, unsigned int &p1,
                                                unsigned int &p2) {
    unsigned int a0 = __float_as_uint(f0), b0 = __float_as_uint(f1);
    unsigned int ah = a0 & 0xffff0000u,   bh = b0 & 0xffff0000u;
    float fa1 = f0 - __uint_as_float(ah);
    float fb1 = f1 - __uint_as_float(bh);
    unsigned int a1 = __float_as_uint(fa1), b1 = __float_as_uint(fb1);
    unsigned int am = a1 & 0xffff0000u,     bm = b1 & 0xffff0000u;
    float fa2 = fa1 - __uint_as_float(am);
    float fb2 = fb1 - __uint_as_float(bm);
    p0 = (a0 >> 16) | bh;
    p1 = (a1 >> 16) | bm;
    p2 = (__float_as_uint(fa2) >> 16) | (__float_as_uint(fb2) & 0xffff0000u);
}

// 8 fp32 -> three 8-bf16 fragments (k ascending in element order)
static __device__ __forceinline__ void cvt8(float4 u, float4 v, V4 &q0, V4 &q1, V4 &q2) {
    split3x2(u.x, u.y, q0.u.x, q1.u.x, q2.u.x);
    split3x2(u.z, u.w, q0.u.y, q1.u.y, q2.u.y);
    split3x2(v.x, v.y, q0.u.z, q1.u.z, q2.u.z);
    split3x2(v.z, v.w, q0.u.w, q1.u.w, q2.u.w);
}

#define MM(ACC, A, B) ACC = __builtin_amdgcn_mfma_f32_32x32x16_bf16((A), (B), ACC, 0, 0, 0)

// 6 significant products of the 3x3 split over two accumulator chains
#define MM6(A0, A1, A2, B0, B1, B2)                                \
    MM(accA, (A0).s, (B0).s); MM(accB, (A0).s, (B1).s);            \
    MM(accA, (A1).s, (B0).s); MM(accB, (A0).s, (B2).s);            \
    MM(accA, (A1).s, (B1).s); MM(accB, (A2).s, (B0).s);

// ---- prep: W [2048][64] fp32 -> fragment-ordered 3-level bf16 split in d_ws ----
__global__ __launch_bounds__(256)
void wsplit_kernel(const float* __restrict__ W, unsigned char* __restrict__ ws) {
    const int t  = blockIdx.x * 256 + threadIdx.x;   // 16384 threads
    const int e  = t & 63;
    const int ko = t >> 6;                           // k-octet 0..255
    const int k0 = ko * 8;
    float f[8];
#pragma unroll
    for (int j = 0; j < 8; ++j) f[j] = W[(size_t)(k0 + j) * EEXP + e];  // coalesced per j
    V4 q0, q1, q2;
    cvt8(make_float4(f[0], f[1], f[2], f[3]),
         make_float4(f[4], f[5], f[6], f[7]), q0, q1, q2);
    const int c  = k0 >> 6;
    const int kg = (k0 >> 4) & 3;
    const int h  = (k0 >> 3) & 1;
    const int et = e >> 5;
    const int ln = h * 32 + (e & 31);
    unsigned char* d = ws + (size_t)(((((c * 4 + kg) * 2 + et) * 64) + ln) * 48);
    *(uint4*)(d +  0) = q0.u;
    *(uint4*)(d + 16) = q1.u;
    *(uint4*)(d + 32) = q2.u;
}

__global__ __launch_bounds__(512, 4)
void router_kernel(const float* __restrict__ x,
                   const unsigned char* __restrict__ wsplit,
                   const float* __restrict__ bias_v,
                   float* __restrict__ mask_out,
                   float* __restrict__ idx_out) {
    __shared__ __align__(16) float ep[8192];   // 32 KB, epilogue only

    const int tid  = threadIdx.x;
    const int lane = tid & 63;
    const int w    = __builtin_amdgcn_readfirstlane(tid >> 6);
    const int kg   = w & 3;        // k16-group within chunk
    const int et   = w >> 2;       // expert half
    const int row0 = blockIdx.x * RB;
    const int l31  = lane & 31;
    const int h    = lane >> 5;

    // A (x) from global: MFMA 32x32x16 A layout row=lane&31, k=8h+j
    const float* xp = x + (size_t)(row0 + l31) * DDIM + kg * 16 + h * 8;
    // B fragments pre-split in ws; wave reads 3KB contiguous per chunk
    const unsigned char* wp = wsplit + (size_t)(((kg * 2 + et) * 64 + lane) * 48);

    f32x16 accA, accB;
#pragma unroll
    for (int i = 0; i < 16; ++i) { accA[i] = 0.f; accB[i] = 0.f; }

    // ---- prologue: fill 2 pipeline slots (chunks 0 and 1) ----
    float4 x0a = *(const float4*)(xp);
    float4 x0b = *(const float4*)(xp + 4);
    V4 b00, b01, b02, b10, b11, b12;
    b00.u = *(const uint4*)(wp);
    b01.u = *(const uint4*)(wp + 16);
    b02.u = *(const uint4*)(wp + 32);
    float4 x1a = *(const float4*)(xp + KC);
    float4 x1b = *(const float4*)(xp + KC + 4);
    b10.u = *(const uint4*)(wp + CHSTRIDE);
    b11.u = *(const uint4*)(wp + CHSTRIDE + 16);
    b12.u = *(const uint4*)(wp + CHSTRIDE + 32);

#pragma unroll 1
    for (int c = 0; c < NCH; c += 2) {
        V4 a0, a1, a2;
        // ---- chunk c (slot 0) ----
        cvt8(x0a, x0b, a0, a1, a2);
        if (c + 2 < NCH) {                       // x prefetch early (regs now free)
            x0a = *(const float4*)(xp + (c + 2) * KC);
            x0b = *(const float4*)(xp + (c + 2) * KC + 4);
        }
        MM6(a0, a1, a2, b00, b01, b02)
        if (c + 2 < NCH) {                       // B prefetch after B consumed
            const unsigned char* q = wp + (size_t)(c + 2) * CHSTRIDE;
            b00.u = *(const uint4*)(q);
            b01.u = *(const uint4*)(q + 16);
            b02.u = *(const uint4*)(q + 32);
        }
        // ---- chunk c+1 (slot 1) ----
        cvt8(x1a, x1b, a0, a1, a2);
        if (c + 3 < NCH) {
            x1a = *(const float4*)(xp + (c + 3) * KC);
            x1b = *(const float4*)(xp + (c + 3) * KC + 4);
        }
        MM6(a0, a1, a2, b10, b11, b12)
        if (c + 3 < NCH) {
            const unsigned char* q = wp + (size_t)(c + 3) * CHSTRIDE;
            b10.u = *(const uint4*)(q);
            b11.u = *(const uint4*)(q + 16);
            b12.u = *(const uint4*)(q + 32);
        }
    }

    // ---- epilogue: merge chains, reduce 4 kg-partials in LDS, softmax + top2 ----
    // C/D layout (m74/m101): col = lane&31, row = (reg&3) + 8*(reg>>2) + 4*(lane>>5)
#pragma unroll
    for (int r = 0; r < 16; ++r) {
        const int rowl = (r & 3) + 8 * (r >> 2) + 4 * h;
        ep[kg * 2048 + rowl * 64 + et * 32 + l31] = accA[r] + accB[r];
    }
    __syncthreads();

    const float bias = bias_v[lane];
#pragma unroll
    for (int rr = 0; rr < 4; ++rr) {
        const int rl  = w * 4 + rr;            // 0..31 local row
        const int row = row0 + rl;
        float logit = bias + ep[rl * 64 + lane]
                           + ep[2048 + rl * 64 + lane]
                           + ep[4096 + rl * 64 + lane]
                           + ep[6144 + rl * 64 + lane];

        float m = logit;
#pragma unroll
        for (int off = 32; off >= 1; off >>= 1) m = fmaxf(m, __shfl_xor(m, off));
        float ex = __expf(logit - m);
        float s = ex;
#pragma unroll
        for (int off = 32; off >= 1; off >>= 1) s += __shfl_xor(s, off);
        float gate = ex / s;

        float v1 = logit; int i1 = lane;
#pragma unroll
        for (int off = 32; off >= 1; off >>= 1) {
            float ov = __shfl_xor(v1, off);
            int   oi = __shfl_xor(i1, off);
            if (ov > v1 || (ov == v1 && oi < i1)) { v1 = ov; i1 = oi; }
        }
        float v2 = (lane == i1) ? -INFINITY : logit; int i2 = lane;
#pragma unroll
        for (int off = 32; off >= 1; off >>= 1) {
            float ov = __shfl_xor(v2, off);
            int   oi = __shfl_xor(i2, off);
            if (ov > v2 || (ov == v2 && oi < i2)) { v2 = ov; i2 = oi; }
        }

        float outv = (lane == i1 || lane == i2) ? gate : 0.0f;
        mask_out[(size_t)row * EEXP + lane] = outv;
        if (lane == 0) {
            idx_out[row * 2 + 0] = (float)i1;
            idx_out[row * 2 + 1] = (float)i2;
        }
    }
}

extern "C" void kernel_launch(void* const* d_in, const int* in_sizes, int n_in,
                              void* d_out, int out_size, void* d_ws, size_t ws_size,
                              hipStream_t stream) {
    const float* x = (const float*)d_in[0];
    const float* W = (const float*)d_in[1];
    const float* b = (const float*)d_in[2];
    float* mask_out = (float*)d_out;
    float* idx_out  = mask_out + (size_t)NROWS * EEXP;
    unsigned char* ws = (unsigned char*)d_ws;   // needs 768 KB

    wsplit_kernel<<<dim3(64), dim3(256), 0, stream>>>(W, ws);
    router_kernel<<<dim3(NROWS / RB), dim3(512), 0, stream>>>(x, ws, b, mask_out, idx_out);
}